// Round 4
// baseline (169.023 us; speedup 1.0000x reference)
//
#include <hip/hip_runtime.h>
#include <stdint.h>

#define NGRAPH 512
#define NN 64
#define INCH 256
#define TOPK 20
#define EPR 655360
#define NROWS 32768
// ws: [0,64KB) W bf16 frag-ordered; [64KB,64KB+16MB) xl then xr f32 [32768][64]
#define WS_NEED ((size_t)65536 + (size_t)16777216)

typedef __attribute__((ext_vector_type(8))) short bf16x8;
typedef __attribute__((ext_vector_type(4))) float f32x4;

static __device__ __forceinline__ uint32_t f2bfbits(float f) {
  uint32_t u = __float_as_uint(f);
  return (u + 0x7FFFu + ((u >> 16) & 1u)) >> 16;     // RNE
}
static __device__ __forceinline__ uint32_t pk2(float a, float b) {
  return f2bfbits(a) | (f2bfbits(b) << 16);
}
static __device__ __forceinline__ float keyalpha(uint32_t k) {
  uint32_t ub = (k & 0x80000000u) ? (k ^ 0x80000000u) : ~k;
  return __uint_as_float(ub & 0xFFFFFFC0u);
}

// xor-butterfly exchange; LDS only for j==4 (quad_perm j=1,2; row_ror:8 j=8;
// permlane16/32_swap j=16,32)
static __device__ __forceinline__ uint32_t bflyu(uint32_t v, const int j, const int lane) {
  if (j == 1)
    return (uint32_t)__builtin_amdgcn_update_dpp(0, (int)v, 0xB1, 0xF, 0xF, true);
  if (j == 2)
    return (uint32_t)__builtin_amdgcn_update_dpp(0, (int)v, 0x4E, 0xF, 0xF, true);
  if (j == 8)
    return (uint32_t)__builtin_amdgcn_update_dpp(0, (int)v, 0x128, 0xF, 0xF, true);
#if __has_builtin(__builtin_amdgcn_permlane16_swap)
  if (j == 16) {
    auto r = __builtin_amdgcn_permlane16_swap((unsigned)v, (unsigned)v, false, false);
    return (uint32_t)(((lane >> 4) & 1) ? r[0] : r[1]);
  }
#endif
#if __has_builtin(__builtin_amdgcn_permlane32_swap)
  if (j == 32) {
    auto r = __builtin_amdgcn_permlane32_swap((unsigned)v, (unsigned)v, false, false);
    return (uint32_t)((lane & 32) ? r[0] : r[1]);
  }
#endif
  return (uint32_t)__shfl_xor((int)v, j);
}
static __device__ __forceinline__ float bflyf(float v, const int j, const int lane) {
  return __uint_as_float(bflyu(__float_as_uint(v), j, lane));
}
static __device__ __forceinline__ float redsum64(float v, const int lane) {
  v += bflyf(v, 1, lane);
  v += bflyf(v, 2, lane);
  v += bflyf(v, 4, lane);
  v += bflyf(v, 8, lane);
  v += bflyf(v, 16, lane);
  v += bflyf(v, 32, lane);
  return v;
}

// ---- W -> bf16, MFMA-fragment order: uint4 idx = half*2048 + ks*256 + ct*64 + quad*16 + lo
__global__ __launch_bounds__(256) void wpack2(const float* __restrict__ Wl,
                                              const float* __restrict__ Wr,
                                              uint4* __restrict__ wsW) {
  const int t = blockIdx.x * 256 + threadIdx.x;      // 0..4095
  const int lo = t & 15, quad = (t >> 4) & 3, ct = (t >> 6) & 3;
  const int ks = (t >> 8) & 7, half = (t >> 11) & 1;
  const int n = ct * 16 + lo, k0 = ks * 32 + quad * 8;
  const float* src = half ? Wr : Wl;
  const float4* s4 = (const float4*)(src + (size_t)n * INCH + k0);
  float4 a0 = s4[0], a1 = s4[1];
  wsW[t] = (uint4){ pk2(a0.x, a0.y), pk2(a0.z, a0.w), pk2(a1.x, a1.y), pk2(a1.z, a1.w) };
}

// ================= kernel A: xl/xr GEMM, no LDS, no barriers =====================
__global__ __launch_bounds__(512, 4) void xlr_gemm(
    const float* __restrict__ x,    // [32768,256]
    const uint4* __restrict__ wsV,  // W frag-ordered
    const float* __restrict__ blv,
    const float* __restrict__ brv,
    float* __restrict__ xlr)        // f32 [2][32768][64]
{
  const int b    = blockIdx.x;
  const int t    = threadIdx.x;
  const int w    = t >> 6;              // wave 0..7
  const int lane = t & 63;
  const int quad = lane >> 4;
  const int lo   = lane & 15;
  const int nodeBase = b * NN;
  const int half = w >> 2;              // 0 -> xl, 1 -> xr
  const int r0   = (w & 3) * 16;

  f32x4 acc[4];
  #pragma unroll
  for (int ct = 0; ct < 4; ++ct) acc[ct] = (f32x4){0.f, 0.f, 0.f, 0.f};

  #pragma unroll
  for (int ks = 0; ks < 8; ++ks) {
    const int k0 = ks * 32 + quad * 8;
    const float* ap = x + (size_t)(nodeBase + r0 + lo) * INCH + k0;
    float4 a0 = *(const float4*)ap;
    float4 a1 = *(const float4*)(ap + 4);
    uint4 au = { pk2(a0.x, a0.y), pk2(a0.z, a0.w), pk2(a1.x, a1.y), pk2(a1.z, a1.w) };
    bf16x8 afrag = __builtin_bit_cast(bf16x8, au);
    #pragma unroll
    for (int ct = 0; ct < 4; ++ct) {
      uint4 bu = wsV[half * 2048 + ks * 256 + ct * 64 + quad * 16 + lo]; // dense 1KB/instr
      bf16x8 bfrag = __builtin_bit_cast(bf16x8, bu);
      acc[ct] = __builtin_amdgcn_mfma_f32_16x16x32_bf16(afrag, bfrag, acc[ct], 0, 0, 0);
    }
  }

  // C/D: col = ct*16+lo -> d, row = quad*4+rg -> node; + bias; straight to global
  const float* bias = half ? brv : blv;
  float* dst = xlr + (size_t)half * ((size_t)NROWS * 64);
  #pragma unroll
  for (int ct = 0; ct < 4; ++ct) {
    const int d = ct * 16 + lo;
    const float bb = bias[d];
    #pragma unroll
    for (int rg = 0; rg < 4; ++rg)
      dst[(size_t)(nodeBase + r0 + quad * 4 + rg) * 64 + d] = acc[ct][rg] + bb;
  }
}

// ============ kernel B: one wave per row; alpha + top-20 + softmax ===============
// alpha'[i][j] = 0.6*Sr_j + 0.4*sum_d a_d|xl_i_d + xr_j_d|   (Sl_i dropped:
// row-uniform shift -> softmax and ranking invariant)
__global__ __launch_bounds__(256, 4) void alphasort(
    const float* __restrict__ xlr,  // xl [32768][64] then xr [32768][64]
    const float* __restrict__ att,
    float* __restrict__ out)
{
  const int lane = threadIdx.x & 63;
  const int row  = __builtin_amdgcn_readfirstlane(
      (int)(blockIdx.x << 2) + (int)(threadIdx.x >> 6));   // 0..32767, wave-uniform
  const int i        = row & 63;                           // diagonal index
  const int nodeBase = row - i;

  // lane j preloads its xr row (16 KB/graph, L1-shared across the block's 4 waves)
  const float* xrp = xlr + (size_t)NROWS * 64 + (size_t)(nodeBase + lane) * 64;
  f32x4 xrv[16];
  #pragma unroll
  for (int c = 0; c < 16; ++c) xrv[c] = *(const f32x4*)(xrp + c * 4);

  const float* xlp = xlr + (size_t)row * 64;               // uniform -> s_load

  float pa0 = 0.f, pa1 = 0.f, sr0 = 0.f, sr1 = 0.f;
  #pragma unroll
  for (int d = 0; d < 64; d += 2) {
    const float a0 = att[d], a1 = att[d + 1];              // SGPR
    const float l0 = xlp[d], l1 = xlp[d + 1];              // SGPR
    const float x0 = xrv[d >> 2][d & 3];
    const float x1 = xrv[(d + 1) >> 2][(d + 1) & 3];
    pa0 = fmaf(a0, fabsf(l0 + x0), pa0);
    sr0 = fmaf(a0, x0, sr0);
    pa1 = fmaf(a1, fabsf(l1 + x1), pa1);
    sr1 = fmaf(a1, x1, sr1);
  }
  const float aq = 0.6f * (sr0 + sr1) + 0.4f * (pa0 + pa1);

  // order-preserving key, asc-index tie-break, diagonal excluded
  uint32_t key;
  {
    const uint32_t u = __float_as_uint(aq);
    uint32_t kk = u ^ ((uint32_t)((int32_t)u >> 31) | 0x80000000u);
    kk = (kk & 0xFFFFFFC0u) | (uint32_t)(63 - lane);
    key = (lane == i) ? 0u : kk;
  }

  // bitonic sort 64 desc (only j==4 stages touch the LDS pipe)
  #pragma unroll
  for (int k = 2; k <= 64; k <<= 1) {
    #pragma unroll
    for (int j = k >> 1; j >= 1; j >>= 1) {
      const bool keep_max = (((lane & k) == 0) == ((lane & j) == 0));
      const uint32_t p = bflyu(key, j, lane);
      const uint32_t mx = (key > p) ? key : p;
      const uint32_t mn = (key > p) ? p : key;
      key = keep_max ? mx : mn;
    }
  }

  // m = max(top, diagonal) (matches segment_max incl. self loop);
  // S = sum_j exp(alpha - m) over all 64 (incl. self loop)
  const uint32_t tk = (uint32_t)__builtin_amdgcn_readlane((int)key, 0);
  const float adiag = __int_as_float(
      __builtin_amdgcn_readlane(__float_as_int(aq), i));
  const float m  = fmaxf(keyalpha(tk), adiag);
  const float Sv = redsum64(__expf(aq - m), lane);

  if (lane < TOPK) {
    const float alpha = keyalpha(key);
    const int jj = 63 - (int)(key & 63u);
    const float va = __expf(alpha - m) * (1.0f / Sv);
    out[(size_t)row * 20 + lane] = (float)row;
    out[(size_t)EPR + (size_t)row * 20 + lane] = (float)(nodeBase + jj);
    out[2 * (size_t)EPR + (size_t)row * 20 + lane] = va;
  }
}

// ================= fallback: Round-3 fused kernel (ws too small) =================
#define XLR 0
#define XRR 4352
#define SMEM_DW 8704

__global__ __launch_bounds__(512, 4) void gat_fused_fb(
    const float* __restrict__ x, const uint4* __restrict__ wsV,
    const float* __restrict__ blv, const float* __restrict__ brv,
    const float* __restrict__ att, float* __restrict__ out)
{
  __shared__ __align__(16) uint32_t smemU[SMEM_DW];
  float* smemF = (float*)smemU;
  const int b = blockIdx.x, t = threadIdx.x;
  const int w = t >> 6, lane = t & 63, quad = lane >> 4, lo = lane & 15;
  const int nodeBase = b * NN;
  const float attv = att[lane];
  const int half = w >> 2, r0 = (w & 3) * 16;

  f32x4 acc[4];
  #pragma unroll
  for (int ct = 0; ct < 4; ++ct) acc[ct] = (f32x4){0.f, 0.f, 0.f, 0.f};
  #pragma unroll
  for (int ks = 0; ks < 8; ++ks) {
    const int k0 = ks * 32 + quad * 8;
    const float* ap = x + (size_t)(nodeBase + r0 + lo) * INCH + k0;
    float4 a0 = *(const float4*)ap;
    float4 a1 = *(const float4*)(ap + 4);
    uint4 au = { pk2(a0.x, a0.y), pk2(a0.z, a0.w), pk2(a1.x, a1.y), pk2(a1.z, a1.w) };
    bf16x8 afrag = __builtin_bit_cast(bf16x8, au);
    #pragma unroll
    for (int ct = 0; ct < 4; ++ct) {
      uint4 bu = wsV[half * 2048 + ks * 256 + ct * 64 + quad * 16 + lo];
      bf16x8 bfrag = __builtin_bit_cast(bf16x8, bu);
      acc[ct] = __builtin_amdgcn_mfma_f32_16x16x32_bf16(afrag, bfrag, acc[ct], 0, 0, 0);
    }
  }
  {
    const float* bias = half ? brv : blv;
    const int dstBase = half ? XRR : XLR;
    #pragma unroll
    for (int ct = 0; ct < 4; ++ct) {
      const int d = ct * 16 + lo;
      const float bb = bias[d];
      #pragma unroll
      for (int rg = 0; rg < 4; ++rg)
        smemF[dstBase + (r0 + quad * 4 + rg) * 68 + d] = acc[ct][rg] + bb;
    }
  }
  __syncthreads();

  const int rB = w * 8;
  float xlv[8];
  #pragma unroll
  for (int q = 0; q < 8; ++q) xlv[q] = smemF[XLR + (rB + q) * 68 + lane];
  float sl[8];
  #pragma unroll
  for (int q = 0; q < 8; ++q) sl[q] = redsum64(attv * xlv[q], lane);

  float pacc[8];
  #pragma unroll
  for (int q = 0; q < 8; ++q) pacc[q] = 0.f;
  float srp = 0.f;
  const int xrb = XRR + lane * 68;
  #pragma unroll
  for (int c = 0; c < 4; ++c) {
    f32x4 xrc[4];
    #pragma unroll
    for (int g = 0; g < 4; ++g) xrc[g] = *(const f32x4*)&smemF[xrb + c * 16 + g * 4];
    #pragma unroll
    for (int dl = 0; dl < 16; ++dl) {
      const int d = c * 16 + dl;
      const float xv = xrc[dl >> 2][dl & 3];
      const float av = __int_as_float(__builtin_amdgcn_readlane(__float_as_int(attv), d));
      srp = fmaf(av, xv, srp);
      #pragma unroll
      for (int q = 0; q < 8; ++q) {
        const float xls = __int_as_float(
            __builtin_amdgcn_readlane(__float_as_int(xlv[q]), d));
        pacc[q] = fmaf(av, fabsf(xls + xv), pacc[q]);
      }
    }
  }
  float aq[8];
  #pragma unroll
  for (int q = 0; q < 8; ++q) aq[q] = 0.6f * (sl[q] + srp) + 0.4f * pacc[q];

  uint32_t key[8];
  #pragma unroll
  for (int q = 0; q < 8; ++q) {
    const uint32_t u = __float_as_uint(aq[q]);
    uint32_t kk = u ^ ((uint32_t)((int32_t)u >> 31) | 0x80000000u);
    kk = (kk & 0xFFFFFFC0u) | (uint32_t)(63 - lane);
    key[q] = (lane == rB + q) ? 0u : kk;
  }
  #pragma unroll
  for (int k = 2; k <= 64; k <<= 1) {
    #pragma unroll
    for (int j = k >> 1; j >= 1; j >>= 1) {
      const bool keep_max = (((lane & k) == 0) == ((lane & j) == 0));
      #pragma unroll
      for (int q = 0; q < 8; ++q) {
        const uint32_t p = bflyu(key[q], j, lane);
        const uint32_t mx = (key[q] > p) ? key[q] : p;
        const uint32_t mn = (key[q] > p) ? p : key[q];
        key[q] = keep_max ? mx : mn;
      }
    }
  }
  float mq[8], Sq[8];
  #pragma unroll
  for (int q = 0; q < 8; ++q) {
    const uint32_t tk = (uint32_t)__builtin_amdgcn_readlane((int)key[q], 0);
    const float adiag = __int_as_float(
        __builtin_amdgcn_readlane(__float_as_int(aq[q]), rB + q));
    mq[q] = fmaxf(keyalpha(tk), adiag);
    Sq[q] = redsum64(__expf(aq[q] - mq[q]), lane);
  }
  if (lane < TOPK) {
    #pragma unroll
    for (int q = 0; q < 8; ++q) {
      const int g = nodeBase + rB + q;
      const float alpha = keyalpha(key[q]);
      const int jj = 63 - (int)(key[q] & 63u);
      const float va = __expf(alpha - mq[q]) * (1.0f / Sq[q]);
      out[(size_t)g * 20 + lane] = (float)g;
      out[(size_t)EPR + (size_t)g * 20 + lane] = (float)(nodeBase + jj);
      out[2 * (size_t)EPR + (size_t)g * 20 + lane] = va;
    }
  }
}

extern "C" void kernel_launch(void* const* d_in, const int* in_sizes, int n_in,
                              void* d_out, int out_size, void* d_ws, size_t ws_size,
                              hipStream_t stream) {
  const float* x   = (const float*)d_in[0];
  // d_in[1] = edge_index, d_in[2] = batch: fully-connected structure is implicit
  const float* Wl  = (const float*)d_in[3];
  const float* bl  = (const float*)d_in[4];
  const float* Wr  = (const float*)d_in[5];
  const float* br  = (const float*)d_in[6];
  const float* att = (const float*)d_in[7];
  uint4* wsW = (uint4*)d_ws;

  wpack2<<<dim3(16), dim3(256), 0, stream>>>(Wl, Wr, wsW);
  if (ws_size >= WS_NEED) {
    float* xlr = (float*)((char*)d_ws + 65536);
    xlr_gemm<<<dim3(NGRAPH), dim3(512), 0, stream>>>(x, wsW, bl, br, xlr);
    alphasort<<<dim3(8192), dim3(256), 0, stream>>>(xlr, att, (float*)d_out);
  } else {
    gat_fused_fb<<<dim3(NGRAPH), dim3(512), 0, stream>>>(x, wsW, bl, br, att,
                                                         (float*)d_out);
  }
}

// Round 5
// 119.444 us; speedup vs baseline: 1.4151x; 1.4151x over previous
//
#include <hip/hip_runtime.h>
#include <stdint.h>

#define NGRAPH 512
#define NN 64
#define INCH 256
#define TOPK 20
#define EPR 655360

typedef __attribute__((ext_vector_type(8))) short bf16x8;
typedef __attribute__((ext_vector_type(4))) float f32x4;

// ---- LDS map (dword offsets), 16512 dwords = 64.5 KB -> 2 blocks/CU
// XBF: bf16-packed x tile [64 row][128 dw], dword-swizzled: dw = c2 ^ ((row&7)<<2)
// XLR/XRR: f32 [64 row][65] (stride 65 -> conflict-free b32 and 2-way b128)
#define XBF 0
#define XLR 8192
#define XRR 12352
#define SMEM_DW 16512

static __device__ __forceinline__ uint32_t f2bfbits(float f) {
  uint32_t u = __float_as_uint(f);
  return (u + 0x7FFFu + ((u >> 16) & 1u)) >> 16;     // RNE
}
static __device__ __forceinline__ uint32_t pk2(float a, float b) {
  return f2bfbits(a) | (f2bfbits(b) << 16);
}
static __device__ __forceinline__ float keyalpha(uint32_t k) {
  uint32_t ub = (k & 0x80000000u) ? (k ^ 0x80000000u) : ~k;
  return __uint_as_float(ub & 0xFFFFFFC0u);
}

// xor-butterfly exchange; LDS pipe only for j==4
static __device__ __forceinline__ uint32_t bflyu(uint32_t v, const int j, const int lane) {
  if (j == 1)
    return (uint32_t)__builtin_amdgcn_update_dpp(0, (int)v, 0xB1, 0xF, 0xF, true);
  if (j == 2)
    return (uint32_t)__builtin_amdgcn_update_dpp(0, (int)v, 0x4E, 0xF, 0xF, true);
  if (j == 8)
    return (uint32_t)__builtin_amdgcn_update_dpp(0, (int)v, 0x128, 0xF, 0xF, true);
#if __has_builtin(__builtin_amdgcn_permlane16_swap)
  if (j == 16) {
    auto r = __builtin_amdgcn_permlane16_swap((unsigned)v, (unsigned)v, false, false);
    return (uint32_t)(((lane >> 4) & 1) ? r[0] : r[1]);
  }
#endif
#if __has_builtin(__builtin_amdgcn_permlane32_swap)
  if (j == 32) {
    auto r = __builtin_amdgcn_permlane32_swap((unsigned)v, (unsigned)v, false, false);
    return (uint32_t)((lane & 32) ? r[0] : r[1]);
  }
#endif
  return (uint32_t)__shfl_xor((int)v, j);
}
static __device__ __forceinline__ float bflyf(float v, const int j, const int lane) {
  return __uint_as_float(bflyu(__float_as_uint(v), j, lane));
}
static __device__ __forceinline__ float redsum64(float v, const int lane) {
  v += bflyf(v, 1, lane);
  v += bflyf(v, 2, lane);
  v += bflyf(v, 4, lane);
  v += bflyf(v, 8, lane);
  v += bflyf(v, 16, lane);
  v += bflyf(v, 32, lane);
  return v;
}

// ---- W -> bf16, MFMA-fragment order: uint4 idx = half*2048 + ks*256 + ct*64 + quad*16 + lo
__global__ __launch_bounds__(256) void wpack2(const float* __restrict__ Wl,
                                              const float* __restrict__ Wr,
                                              uint4* __restrict__ wsW) {
  const int t = blockIdx.x * 256 + threadIdx.x;      // 0..4095
  const int lo = t & 15, quad = (t >> 4) & 3, ct = (t >> 6) & 3;
  const int ks = (t >> 8) & 7, half = (t >> 11) & 1;
  const int n = ct * 16 + lo, k0 = ks * 32 + quad * 8;
  const float* src = half ? Wr : Wl;
  const float4* s4 = (const float4*)(src + (size_t)n * INCH + k0);
  float4 a0 = s4[0], a1 = s4[1];
  wsW[t] = (uint4){ pk2(a0.x, a0.y), pk2(a0.z, a0.w), pk2(a1.x, a1.y), pk2(a1.z, a1.w) };
}

__global__ __launch_bounds__(512, 4) void gat3(
    const float* __restrict__ x,    // [32768,256]
    const uint4* __restrict__ wsV,  // W frag-ordered (L2-resident)
    const float* __restrict__ blv,
    const float* __restrict__ brv,
    const float* __restrict__ att,
    float* __restrict__ out)        // f32: [idx_i EPR | idx_j EPR | att EPR]
{
  __shared__ __align__(16) uint32_t smemU[SMEM_DW];
  float* smemF = (float*)smemU;

  const int b    = blockIdx.x;
  const int t    = threadIdx.x;
  const int w    = t >> 6;              // wave 0..7
  const int lane = t & 63;
  const int quad = lane >> 4;
  const int lo   = lane & 15;
  const int nodeBase = b * NN;

  // -------- stage: x[64][256] f32, DENSE loads (1 KB/wave/instr) -> bf16 LDS ------
  {
    const float* xg = x + (size_t)nodeBase * INCH;
    #pragma unroll
    for (int i = 0; i < 8; ++i) {
      const int fd = i * 2048 + t * 4;               // flat dword in tile
      float4 v = *(const float4*)(xg + fd);
      const int row = fd >> 8;                       // i*8 + (t>>6)
      const int c2  = (fd & 255) >> 1;               // (t&63)*2, even
      const int dw  = row * 128 + (c2 ^ ((row & 7) << 2));
      *(uint2*)&smemU[XBF + dw] = (uint2){ pk2(v.x, v.y), pk2(v.z, v.w) };
    }
  }
  __syncthreads();                                   // XBF ready

  // -------- phase 1: MFMA GEMM from LDS A-frags + dense global B-frags ------------
  const int half = w >> 2;              // 0 -> Wl/xl, 1 -> Wr/xr
  const int r0   = (w & 3) * 16;

  f32x4 acc[4];
  #pragma unroll
  for (int ct = 0; ct < 4; ++ct) acc[ct] = (f32x4){0.f, 0.f, 0.f, 0.f};

  #pragma unroll
  for (int ks = 0; ks < 8; ++ks) {
    const int adw = XBF + (r0 + lo) * 128 + ((ks * 16 + quad * 4) ^ ((lo & 7) << 2));
    uint4 au = *(const uint4*)&smemU[adw];           // conflict-managed ds_read_b128
    bf16x8 afrag = __builtin_bit_cast(bf16x8, au);
    #pragma unroll
    for (int ct = 0; ct < 4; ++ct) {
      uint4 bu = wsV[half * 2048 + ks * 256 + ct * 64 + quad * 16 + lo]; // dense 1KB
      bf16x8 bfrag = __builtin_bit_cast(bf16x8, bu);
      acc[ct] = __builtin_amdgcn_mfma_f32_16x16x32_bf16(afrag, bfrag, acc[ct], 0, 0, 0);
    }
  }

  // epilogue: C/D (col=ct*16+lo -> d, row=quad*4+rg) + bias -> XLR/XRR row-major
  {
    const float* bias = half ? brv : blv;
    const int dstBase = half ? XRR : XLR;
    #pragma unroll
    for (int ct = 0; ct < 4; ++ct) {
      const int d = ct * 16 + lo;
      const float bb = bias[d];
      #pragma unroll
      for (int rg = 0; rg < 4; ++rg)
        smemF[dstBase + (r0 + quad * 4 + rg) * 65 + d] = acc[ct][rg] + bb;
    }
  }
  __syncthreads();                                   // XLR/XRR ready — last barrier

  // ============== phases 2+3, per-wave: wave w owns rows rB..rB+7 ================
  // alpha'[i][j] = 0.6*Sr_j + 0.4*sum_d a_d|xl_i_d + xr_j_d|  (Sl_i dropped:
  // row-uniform shift -> softmax and ranking invariant; validated in R4)
  const int rB = w * 8;

  float xlv[8];
  #pragma unroll
  for (int q = 0; q < 8; ++q)
    xlv[q] = smemF[XLR + (rB + q) * 65 + lane];      // lane d holds xl[rB+q][d]

  float pacc[8];
  #pragma unroll
  for (int q = 0; q < 8; ++q) pacc[q] = 0.f;
  float srp = 0.f;
  const int xrb = XRR + lane * 65;                   // lane j's xr row
  #pragma unroll
  for (int c = 0; c < 4; ++c) {
    f32x4 xrc[4];
    #pragma unroll
    for (int g = 0; g < 4; ++g)
      xrc[g] = *(const f32x4*)&smemF[xrb + c * 16 + g * 4];  // 2-way max (free)
    #pragma unroll
    for (int dl = 0; dl < 16; ++dl) {
      const int d = c * 16 + dl;
      const float xv = xrc[dl >> 2][dl & 3];
      const float ad = att[d];                       // uniform -> s_load/SGPR
      srp = fmaf(ad, xv, srp);
      #pragma unroll
      for (int q = 0; q < 8; ++q) {
        const float xls = __int_as_float(
            __builtin_amdgcn_readlane(__float_as_int(xlv[q]), d));
        pacc[q] = fmaf(ad, fabsf(xls + xv), pacc[q]);
      }
    }
  }

  float aq[8];
  #pragma unroll
  for (int q = 0; q < 8; ++q)
    aq[q] = 0.6f * srp + 0.4f * pacc[q];

  // order-preserving keys, asc-index tie-break, diagonal excluded
  uint32_t key[8];
  #pragma unroll
  for (int q = 0; q < 8; ++q) {
    const uint32_t u = __float_as_uint(aq[q]);
    uint32_t kk = u ^ ((uint32_t)((int32_t)u >> 31) | 0x80000000u);
    kk = (kk & 0xFFFFFFC0u) | (uint32_t)(63 - lane);
    key[q] = (lane == rB + q) ? 0u : kk;
  }

  // bitonic sort 64 desc; DPP/permlane exchanges, LDS pipe only for j==4
  #pragma unroll
  for (int k = 2; k <= 64; k <<= 1) {
    #pragma unroll
    for (int j = k >> 1; j >= 1; j >>= 1) {
      const bool keep_max = (((lane & k) == 0) == ((lane & j) == 0));
      #pragma unroll
      for (int q = 0; q < 8; ++q) {
        const uint32_t p = bflyu(key[q], j, lane);
        const uint32_t mx = (key[q] > p) ? key[q] : p;
        const uint32_t mn = (key[q] > p) ? p : key[q];
        key[q] = keep_max ? mx : mn;
      }
    }
  }

  // m = max(top, diagonal); S = sum_j exp(alpha - m) over all 64 (incl. self loop)
  float mq[8], Sq[8];
  #pragma unroll
  for (int q = 0; q < 8; ++q) {
    const uint32_t tk = (uint32_t)__builtin_amdgcn_readlane((int)key[q], 0);
    const float adiag = __int_as_float(
        __builtin_amdgcn_readlane(__float_as_int(aq[q]), rB + q));
    mq[q] = fmaxf(keyalpha(tk), adiag);
    Sq[q] = redsum64(__expf(aq[q] - mq[q]), lane);
  }

  // lanes 0..19 hold top-20 desc; decode + softmax + store (80-B coalesced runs)
  if (lane < TOPK) {
    #pragma unroll
    for (int q = 0; q < 8; ++q) {
      const int g = nodeBase + rB + q;
      const uint32_t kq = key[q];
      const float alpha = keyalpha(kq);
      const int jj = 63 - (int)(kq & 63u);
      const float va = __expf(alpha - mq[q]) * (1.0f / Sq[q]);
      out[(size_t)g * 20 + lane] = (float)g;
      out[(size_t)EPR + (size_t)g * 20 + lane] = (float)(nodeBase + jj);
      out[2 * (size_t)EPR + (size_t)g * 20 + lane] = va;
    }
  }
}

extern "C" void kernel_launch(void* const* d_in, const int* in_sizes, int n_in,
                              void* d_out, int out_size, void* d_ws, size_t ws_size,
                              hipStream_t stream) {
  const float* x   = (const float*)d_in[0];
  // d_in[1] = edge_index, d_in[2] = batch: fully-connected structure is implicit
  const float* Wl  = (const float*)d_in[3];
  const float* bl  = (const float*)d_in[4];
  const float* Wr  = (const float*)d_in[5];
  const float* br  = (const float*)d_in[6];
  const float* att = (const float*)d_in[7];
  uint4* wsW = (uint4*)d_ws;                         // 64 KB: W bf16 frag-ordered

  wpack2<<<dim3(16), dim3(256), 0, stream>>>(Wl, Wr, wsW);
  gat3<<<dim3(NGRAPH), dim3(512), 0, stream>>>(x, wsW, bl, br, att, (float*)d_out);
}